// Round 1
// baseline (484.108 us; speedup 1.0000x reference)
//
#include <hip/hip_runtime.h>
#include <math.h>

// Problem constants
#define NB 1024        // batch
#define DF 64          // D_FEAT
#define WIN 8192       // WINDOW_SIZE
#define LIR 16382      // ir_len = 2*(WIN-1)
#define TBASE 7681     // t_j = TBASE + j
#define NJ 1024        // padded impulse length (real length 1023)
#define INV_MAXSTEPS (1.0f/2799.0f)
#define TWO_PI 6.28318530717958647692f

// ---------------- K0: amps = sigmoid(x@Wa+ba), mean = tanh(x@Wm+bm) ----------------
__global__ void k_head(const float* __restrict__ vel, const float* __restrict__ Kv,
                       const float* __restrict__ Wa, const float* __restrict__ ba,
                       const float* __restrict__ Wm, const float* __restrict__ bm,
                       float* __restrict__ amps, float* __restrict__ mean,
                       float* __restrict__ out_mean) {
    int b = blockIdx.x * 256 + threadIdx.x;
    if (b >= NB) return;
    float sa = ba[0], sm = bm[0];
    #pragma unroll 8
    for (int d = 0; d < DF; ++d) {
        float v = vel[b * DF + d];
        sa = fmaf(v, Wa[d], sa);
        sm = fmaf(v, Wm[d], sm);
    }
    float xk = Kv[b] * INV_MAXSTEPS;
    sa = fmaf(xk, Wa[DF], sa);
    sm = fmaf(xk, Wm[DF], sm);
    float a = 1.0f / (1.0f + expf(-sa));
    float m = tanhf(sm);
    amps[b] = a;
    mean[b] = m;
    out_mean[b] = m;   // second tuple output
}

// ---------------- K1: per-block max of (mean[b] + eps[b,i]) ----------------
__global__ void k_maxpart(const float* __restrict__ eps, const float* __restrict__ mean,
                          float* __restrict__ pmax) {
    __shared__ float red[256];
    int tid = threadIdx.x;
    float m = -INFINITY;
    const int total = NB * WIN;           // 8388608 < 2^31
    const int stride = 1024 * 256;
    for (int idx = blockIdx.x * 256 + tid; idx < total; idx += stride) {
        int b = idx >> 13;                // /WIN
        m = fmaxf(m, mean[b] + eps[idx]);
    }
    red[tid] = m;
    __syncthreads();
    for (int s = 128; s > 0; s >>= 1) {
        if (tid < s) red[tid] = fmaxf(red[tid], red[tid + s]);
        __syncthreads();
    }
    if (tid == 0) pmax[blockIdx.x] = red[0];
}

// ---------------- K1b: final max + build zero-padded normalized noise ----------------
// npad[q] = nz(q - 517), nz(m) = (mean[0]+eps[0][m])/gmax for m in [0,8192), else 0
#define NPAD_N 9240
#define NPAD_SH 517
__global__ void k_npad(const float* __restrict__ pmax, const float* __restrict__ eps,
                       const float* __restrict__ mean, float* __restrict__ npad) {
    __shared__ float red[256];
    int tid = threadIdx.x;
    float m = fmaxf(fmaxf(pmax[tid], pmax[tid + 256]),
                    fmaxf(pmax[tid + 512], pmax[tid + 768]));
    red[tid] = m;
    __syncthreads();
    for (int s = 128; s > 0; s >>= 1) {
        if (tid < s) red[tid] = fmaxf(red[tid], red[tid + s]);
        __syncthreads();
    }
    float inv = 1.0f / red[0];
    float m0 = mean[0];
    for (int q = tid; q < NPAD_N; q += 256) {
        int mm = q - NPAD_SH;
        npad[q] = ((unsigned)mm < (unsigned)WIN) ? (m0 + eps[mm]) * inv : 0.0f;
    }
}

// ---------------- K2: Apart[ks][d][j] = sum_{k in chunk} Waug[d][k] * c_k(t_j) ----------------
// c_k(t) = w_k/LIR * cos(2*pi*((k*t) mod LIR)/LIR), w_k = 1 for k in {0, 8191} else 2
__global__ void k_apart(const float* __restrict__ Wc, const float* __restrict__ bc,
                        float* __restrict__ Apart, int kchunk) {
    int j = blockIdx.x * 256 + threadIdx.x;      // 0..1023
    int k0 = blockIdx.y * kchunk;
    int t = TBASE + j;
    float acc[66];
    #pragma unroll
    for (int d = 0; d < 66; ++d) acc[d] = 0.0f;
    for (int kk = 0; kk < kchunk; ++kk) {
        int k = k0 + kk;
        int p = (k * t) % LIR;                   // exact integer phase (k*t < 2^31)
        float wk = (k == 0 || k == LIR / 2) ? (1.0f / (float)LIR) : (2.0f / (float)LIR);
        float c = wk * cosf((float)p * (TWO_PI / (float)LIR));
        #pragma unroll
        for (int d = 0; d < 65; ++d)
            acc[d] = fmaf(Wc[d * WIN + k], c, acc[d]);
        acc[65] = fmaf(bc[k], c, acc[65]);
    }
    float* o = Apart + (size_t)blockIdx.y * (66 * NJ) + j;
    #pragma unroll
    for (int d = 0; d < 66; ++d) o[d * NJ] = acc[d];
}

// ---------------- K3: Aimp[d][j] = hann(j+2) * sum_ks Apart ; column 1023 zeroed ----------------
__global__ void k_reduce(const float* __restrict__ Apart, float* __restrict__ Aimp, int ksplit) {
    int idx = blockIdx.x * 256 + threadIdx.x;    // 0 .. 66*1024
    float s = 0.0f;
    for (int q = 0; q < ksplit; ++q)
        s += Apart[(size_t)q * (66 * NJ) + idx];
    int j = idx & (NJ - 1);
    float w = 0.5f - 0.5f * cosf((float)(j + 2) * (TWO_PI / 1024.0f));
    if (j == NJ - 1) w = 0.0f;                   // impulse has length 1023; pad with 0
    Aimp[idx] = s * w;
}

// ---------------- K4: imp[b][j] = xaug[b] . Aimp[:,j]  (4 rows b per block) ----------------
__global__ void k_imp(const float* __restrict__ Aimp, const float* __restrict__ vel,
                      const float* __restrict__ Kv, float* __restrict__ imp) {
    int tid = threadIdx.x;
    int b0 = blockIdx.x * 4;
    float acc[4][4];
    #pragma unroll
    for (int bb = 0; bb < 4; ++bb)
        #pragma unroll
        for (int q = 0; q < 4; ++q) acc[bb][q] = 0.0f;
    for (int d = 0; d < 65; ++d) {
        float xv[4];
        #pragma unroll
        for (int bb = 0; bb < 4; ++bb)
            xv[bb] = (d < DF) ? vel[(b0 + bb) * DF + d] : Kv[b0 + bb] * INV_MAXSTEPS;
        #pragma unroll
        for (int q = 0; q < 4; ++q) {
            float av = Aimp[d * NJ + q * 256 + tid];
            #pragma unroll
            for (int bb = 0; bb < 4; ++bb)
                acc[bb][q] = fmaf(xv[bb], av, acc[bb][q]);
        }
    }
    #pragma unroll
    for (int q = 0; q < 4; ++q) {
        float av = Aimp[65 * NJ + q * 256 + tid];
        #pragma unroll
        for (int bb = 0; bb < 4; ++bb)
            imp[(size_t)(b0 + bb) * NJ + q * 256 + tid] = acc[bb][q] + av;
    }
}

// ---------------- K5: out[b][i] = amps[b] * sum_j imp[b][j] * nz(510 + i - j) ----------------
// Per block: one row b, i-tile of 4096. 256 threads x 16 consecutive outputs.
// Noise window staged in LDS with 16B-block XOR swizzle; sliding 20-float register window.
#define R 16
#define ITILE 4096
#define SNZ_BLOCKS 1281    // 5124 floats
__global__ __launch_bounds__(256) void k_conv(const float* __restrict__ imp,
                                              const float* __restrict__ npad,
                                              const float* __restrict__ amps,
                                              float* __restrict__ out) {
    __shared__ float4 simp4[NJ / 4];     // impulse row (1024 floats)
    __shared__ float4 snz4[SNZ_BLOCKS];  // swizzled noise window (5124 floats)
    int tid = threadIdx.x;
    int b = blockIdx.x >> 1;
    int i0 = (blockIdx.x & 1) * ITILE;

    // stage impulse row
    {
        const float4* src = (const float4*)(imp + (size_t)b * NJ);
        simp4[tid] = src[tid];
    }
    // stage noise window: local npad index = global npad index - i0
    {
        const float4* src = (const float4*)npad;
        int base = i0 >> 2;
        for (int q = tid; q < SNZ_BLOCKS; q += 256) {
            float4 v = src[base + q];
            snz4[q ^ ((q >> 3) & 7)] = v;
        }
    }
    __syncthreads();

    float acc[R];
    #pragma unroll
    for (int r = 0; r < R; ++r) acc[r] = 0.0f;

    int il = tid * R;   // local output index within tile
    float nwin[20];     // nwin[s] = nz(510 + i - j - 3 + s), local npad idx = 1024 + il + s (at j=0)
    {
        int blk = (1024 + il) >> 2;
        #pragma unroll
        for (int q = 0; q < 5; ++q) {
            int pb = (blk + q) ^ (((blk + q) >> 3) & 7);
            float4 v = snz4[pb];
            nwin[q * 4 + 0] = v.x; nwin[q * 4 + 1] = v.y;
            nwin[q * 4 + 2] = v.z; nwin[q * 4 + 3] = v.w;
        }
    }

    for (int j = 0; j < NJ; j += 4) {
        float4 ip = simp4[j >> 2];
        float ipv[4] = {ip.x, ip.y, ip.z, ip.w};
        #pragma unroll
        for (int u = 0; u < 4; ++u) {
            #pragma unroll
            for (int r = 0; r < R; ++r)
                acc[r] = fmaf(ipv[u], nwin[3 + r - u], acc[r]);
        }
        // shift window up by 4; fetch next-lower 4 values (for j+4)
        #pragma unroll
        for (int s = 19; s >= 4; --s) nwin[s] = nwin[s - 4];
        int idx = 1020 + il - j;            // local npad idx of new nwin[0]; multiple of 4
        int blk2 = idx >> 2;
        int pb2 = blk2 ^ ((blk2 >> 3) & 7);
        float4 v = snz4[pb2];
        nwin[0] = v.x; nwin[1] = v.y; nwin[2] = v.z; nwin[3] = v.w;
    }

    float a = amps[b];
    float4* o = (float4*)(out + (size_t)b * WIN + i0 + il);
    #pragma unroll
    for (int c = 0; c < 4; ++c) {
        float4 v;
        v.x = a * acc[c * 4 + 0];
        v.y = a * acc[c * 4 + 1];
        v.z = a * acc[c * 4 + 2];
        v.w = a * acc[c * 4 + 3];
        o[c] = v;
    }
}

// ---------------- launch ----------------
extern "C" void kernel_launch(void* const* d_in, const int* in_sizes, int n_in,
                              void* d_out, int out_size, void* d_ws, size_t ws_size,
                              hipStream_t stream) {
    const float* vel = (const float*)d_in[0];
    const float* Kv  = (const float*)d_in[1];
    const float* eps = (const float*)d_in[2];
    const float* Wc  = (const float*)d_in[3];
    const float* bc  = (const float*)d_in[4];
    const float* Wa  = (const float*)d_in[5];
    const float* ba  = (const float*)d_in[6];
    const float* Wm  = (const float*)d_in[7];
    const float* bm  = (const float*)d_in[8];
    float* out = (float*)d_out;

    char* ws = (char*)d_ws;
    float* amps  = (float*)(ws + 0);
    float* mean  = (float*)(ws + 4096);
    float* pmax  = (float*)(ws + 8192);
    float* npad  = (float*)(ws + 12288);            // 9240 floats = 36960 B
    float* Aimp  = (float*)(ws + 49664);            // 66*1024*4 = 270336 B
    char*  region = ws + 49664 + 270336;            // = 320000
    float* Apart = (float*)region;                  // ksplit * 270336 B
    float* imp   = (float*)region;                  // 4 MiB, reuses Apart after K3

    size_t rem = (ws_size > 320000) ? ws_size - 320000 : 0;
    int ksplit = 1;
    while (ksplit < 64 && (size_t)(ksplit * 2) * 270336ull <= rem) ksplit <<= 1;
    int kchunk = WIN / ksplit;

    k_head<<<dim3(4), dim3(256), 0, stream>>>(vel, Kv, Wa, ba, Wm, bm, amps, mean,
                                              out + (size_t)NB * WIN);
    k_maxpart<<<dim3(1024), dim3(256), 0, stream>>>(eps, mean, pmax);
    k_npad<<<dim3(1), dim3(256), 0, stream>>>(pmax, eps, mean, npad);
    k_apart<<<dim3(4, ksplit), dim3(256), 0, stream>>>(Wc, bc, Apart, kchunk);
    k_reduce<<<dim3(264), dim3(256), 0, stream>>>(Apart, Aimp, ksplit);
    k_imp<<<dim3(256), dim3(256), 0, stream>>>(Aimp, vel, Kv, imp);
    k_conv<<<dim3(2048), dim3(256), 0, stream>>>(imp, npad, amps, out);
}

// Round 2
// 335.088 us; speedup vs baseline: 1.4447x; 1.4447x over previous
//
#include <hip/hip_runtime.h>
#include <math.h>

// Problem constants
#define NB 1024        // batch
#define DF 64          // D_FEAT
#define WIN 8192       // WINDOW_SIZE
#define LIR 16382      // ir_len = 2*(WIN-1)
#define TBASE 7681     // t_j = TBASE + j
#define NJ 1024        // padded impulse length (real length 1023)
#define INV_MAXSTEPS (1.0f/2799.0f)
#define TWO_PI 6.28318530717958647692f

// rev-copy geometry: rev[x] = npad[9239-x]; revc[c][x] = rev[x+c], 8 copies, each padded to 9248 elems
#define REVLEN 9248
#define SREV 8212      // B[j][i] = rev[8212 - i + j]

using short8 = __attribute__((ext_vector_type(8))) short;
using f32x4  = __attribute__((ext_vector_type(4))) float;

static __device__ __forceinline__ short f2bf(float x) {
    unsigned u = __float_as_uint(x);
    unsigned r = (u + 0x7fffu + ((u >> 16) & 1u)) >> 16;   // RNE
    return (short)r;
}

// ---------------- K0: amps = sigmoid(x@Wa+ba), mean = tanh(x@Wm+bm) ----------------
__global__ void k_head(const float* __restrict__ vel, const float* __restrict__ Kv,
                       const float* __restrict__ Wa, const float* __restrict__ ba,
                       const float* __restrict__ Wm, const float* __restrict__ bm,
                       float* __restrict__ amps, float* __restrict__ mean,
                       float* __restrict__ out_mean) {
    int b = blockIdx.x * 256 + threadIdx.x;
    if (b >= NB) return;
    float sa = ba[0], sm = bm[0];
    #pragma unroll 8
    for (int d = 0; d < DF; ++d) {
        float v = vel[b * DF + d];
        sa = fmaf(v, Wa[d], sa);
        sm = fmaf(v, Wm[d], sm);
    }
    float xk = Kv[b] * INV_MAXSTEPS;
    sa = fmaf(xk, Wa[DF], sa);
    sm = fmaf(xk, Wm[DF], sm);
    amps[b] = 1.0f / (1.0f + expf(-sa));
    float m = tanhf(sm);
    mean[b] = m;
    out_mean[b] = m;
}

// ---------------- K0b: cos table + zero Aimp ----------------
// costab[p] = (2/LIR) * cos(2*pi*p/LIR) for p in [0,16382); [16382..16384) = 0
__global__ void k_costab(float* __restrict__ costab, float* __restrict__ Aimp) {
    int idx = blockIdx.x * 256 + threadIdx.x;     // 0 .. 83968
    if (idx < 16384) {
        float v = 0.0f;
        if (idx < LIR)
            v = (2.0f / (float)LIR) * cosf((float)idx * (TWO_PI / (float)LIR));
        costab[idx] = v;
    } else {
        int q = idx - 16384;
        if (q < 66 * NJ) Aimp[q] = 0.0f;
    }
}

// ---------------- K1: per-block max of (mean[b] + eps[b,i]), float4 ----------------
__global__ void k_maxpart(const float* __restrict__ eps, const float* __restrict__ mean,
                          float* __restrict__ pmax) {
    __shared__ float red[256];
    int tid = threadIdx.x;
    float m = -INFINITY;
    const int total4 = NB * WIN / 4;
    const int stride = 1024 * 256;
    const float4* e4 = (const float4*)eps;
    for (int idx = blockIdx.x * 256 + tid; idx < total4; idx += stride) {
        int b = idx >> 11;                 // (idx*4)>>13
        float4 v = e4[idx];
        float mm = fmaxf(fmaxf(v.x, v.y), fmaxf(v.z, v.w));
        m = fmaxf(m, mean[b] + mm);
    }
    red[tid] = m;
    __syncthreads();
    for (int s = 128; s > 0; s >>= 1) {
        if (tid < s) red[tid] = fmaxf(red[tid], red[tid + s]);
        __syncthreads();
    }
    if (tid == 0) pmax[blockIdx.x] = red[0];
}

// ---------------- K1b: final max + write 8 shifted reversed bf16 noise copies ----------------
// npadval(q) = (q-517 in [0,8192)) ? (mean0+eps[q-517])/gmax : 0
// revc[c][x] = npadval(9239 - x - c), bf16
__global__ void k_nrev(const float* __restrict__ pmax, const float* __restrict__ eps,
                       const float* __restrict__ mean, short* __restrict__ revc) {
    __shared__ float red[256];
    int tid = threadIdx.x;
    float m = fmaxf(fmaxf(pmax[tid], pmax[tid + 256]),
                    fmaxf(pmax[tid + 512], pmax[tid + 768]));
    red[tid] = m;
    __syncthreads();
    for (int s = 128; s > 0; s >>= 1) {
        if (tid < s) red[tid] = fmaxf(red[tid], red[tid + s]);
        __syncthreads();
    }
    float inv = 1.0f / red[0];
    float m0 = mean[0];
    #pragma unroll
    for (int c = 0; c < 8; ++c) {
        for (int x = tid; x < REVLEN; x += 256) {
            int q = 9239 - x - c;
            int mm = q - 517;
            float v = ((unsigned)mm < (unsigned)WIN) ? (m0 + eps[mm]) * inv : 0.0f;
            revc[c * REVLEN + x] = f2bf(v);
        }
    }
}

// ---------------- K2: Aimp[d][j] += sum_{k in chunk} Waug[d][k] * c_k(t_j)  (atomic) ----------------
__global__ __launch_bounds__(256) void k_apart(const float* __restrict__ Wc,
                                               const float* __restrict__ bc,
                                               const float* __restrict__ costab,
                                               float* __restrict__ Aimp) {
    __shared__ float tab[16384];
    int tid = threadIdx.x;
    for (int q = tid; q < 16384; q += 256) tab[q] = costab[q];
    __syncthreads();

    int j = blockIdx.x * 256 + tid;              // 0..1023
    int t = TBASE + j;
    int k0 = blockIdx.y * 128;
    int p = (k0 * t) % LIR;

    float acc[66];
    #pragma unroll
    for (int d = 0; d < 66; ++d) acc[d] = 0.0f;

    for (int kk = 0; kk < 128; ++kk) {
        int k = k0 + kk;
        float c = tab[p];
        if (k == 0 || k == LIR / 2) c *= 0.5f;
        p += t; if (p >= LIR) p -= LIR;
        #pragma unroll
        for (int d = 0; d < 65; ++d)
            acc[d] = fmaf(Wc[d * WIN + k], c, acc[d]);
        acc[65] = fmaf(bc[k], c, acc[65]);
    }
    #pragma unroll
    for (int d = 0; d < 66; ++d)
        atomicAdd(Aimp + d * NJ + j, acc[d]);
}

// ---------------- K3: Aimp[d][j] *= hann(j+2); column 1023 zeroed (in place) ----------------
__global__ void k_hann(float* __restrict__ Aimp) {
    int idx = blockIdx.x * 256 + threadIdx.x;    // 0 .. 66*1024
    int j = idx & (NJ - 1);
    float w = 0.5f - 0.5f * cosf((float)(j + 2) * (TWO_PI / 1024.0f));
    if (j == NJ - 1) w = 0.0f;
    Aimp[idx] *= w;
}

// ---------------- K4: imp_bf[b][j] = bf16(xaug[b] . Aimp[:,j]) ----------------
__global__ void k_imp(const float* __restrict__ Aimp, const float* __restrict__ vel,
                      const float* __restrict__ Kv, short* __restrict__ imp_bf) {
    int tid = threadIdx.x;
    int b0 = blockIdx.x * 4;
    float acc[4][4];
    #pragma unroll
    for (int bb = 0; bb < 4; ++bb)
        #pragma unroll
        for (int q = 0; q < 4; ++q) acc[bb][q] = 0.0f;
    for (int d = 0; d < 65; ++d) {
        float xv[4];
        #pragma unroll
        for (int bb = 0; bb < 4; ++bb)
            xv[bb] = (d < DF) ? vel[(b0 + bb) * DF + d] : Kv[b0 + bb] * INV_MAXSTEPS;
        #pragma unroll
        for (int q = 0; q < 4; ++q) {
            float av = Aimp[d * NJ + q * 256 + tid];
            #pragma unroll
            for (int bb = 0; bb < 4; ++bb)
                acc[bb][q] = fmaf(xv[bb], av, acc[bb][q]);
        }
    }
    #pragma unroll
    for (int q = 0; q < 4; ++q) {
        float av = Aimp[65 * NJ + q * 256 + tid];
        #pragma unroll
        for (int bb = 0; bb < 4; ++bb)
            imp_bf[(size_t)(b0 + bb) * NJ + q * 256 + tid] = f2bf(acc[bb][q] + av);
    }
}

// ---------------- K5: MFMA GEMM  out[b][i] = amps[b] * sum_j imp[b][j]*rev[8212-i+j] ----------------
// Block = 256 thr = 4 waves (2x2), wave tile 64x64, block tile 128(M=b) x 128(N=i).
// A-frag: lane l holds imp[b0+mf*16+(l&15)][k0+8*(l>>4)+e], e=0..7 -> one 16B load.
// B-frag: lane l holds rev[8212-i+k], i = i0+nf*16+(l&15), k = k0+8*(l>>4)+e -> ascending
//         contiguous in rev; read copy c=(start&7) so the 8-run is 16B-aligned.
__global__ __launch_bounds__(256) void k_gemm(const short* __restrict__ imp_bf,
                                              const short* __restrict__ revc,
                                              const float* __restrict__ amps,
                                              float* __restrict__ out) {
    int tid = threadIdx.x;
    int l = tid & 63, w = tid >> 6;
    int wm = w >> 1, wn = w & 1;
    int lm = l & 15, lg = l >> 4;

    int brow0 = blockIdx.y * 128 + wm * 64;      // M base for this wave
    int icol0 = blockIdx.x * 128 + wn * 64;      // N base for this wave

    const short* pa[4];
    const short* pb[4];
    #pragma unroll
    for (int mf = 0; mf < 4; ++mf)
        pa[mf] = imp_bf + (size_t)(brow0 + mf * 16 + lm) * NJ + 8 * lg;
    #pragma unroll
    for (int nf = 0; nf < 4; ++nf) {
        int i = icol0 + nf * 16 + lm;
        int s0 = SREV - i + 8 * lg;              // at k0 = 0
        int c = s0 & 7;
        pb[nf] = revc + c * REVLEN + (s0 - c);
    }

    f32x4 acc[4][4];
    #pragma unroll
    for (int mf = 0; mf < 4; ++mf)
        #pragma unroll
        for (int nf = 0; nf < 4; ++nf)
            #pragma unroll
            for (int r = 0; r < 4; ++r) acc[mf][nf][r] = 0.0f;

    #pragma unroll 2
    for (int k0 = 0; k0 < NJ; k0 += 32) {
        short8 af[4], bfr[4];
        #pragma unroll
        for (int mf = 0; mf < 4; ++mf)
            af[mf] = *(const short8*)(pa[mf] + k0);
        #pragma unroll
        for (int nf = 0; nf < 4; ++nf)
            bfr[nf] = *(const short8*)(pb[nf] + k0);
        #pragma unroll
        for (int mf = 0; mf < 4; ++mf)
            #pragma unroll
            for (int nf = 0; nf < 4; ++nf)
                acc[mf][nf] = __builtin_amdgcn_mfma_f32_16x16x32_bf16(
                    af[mf], bfr[nf], acc[mf][nf], 0, 0, 0);
    }

    // D layout (verified): col = lane&15, row = 4*(lane>>4) + r
    #pragma unroll
    for (int mf = 0; mf < 4; ++mf) {
        #pragma unroll
        for (int r = 0; r < 4; ++r) {
            int row = brow0 + mf * 16 + 4 * lg + r;
            float a = amps[row];
            #pragma unroll
            for (int nf = 0; nf < 4; ++nf)
                out[(size_t)row * WIN + icol0 + nf * 16 + lm] = a * acc[mf][nf][r];
        }
    }
}

// ---------------- launch ----------------
extern "C" void kernel_launch(void* const* d_in, const int* in_sizes, int n_in,
                              void* d_out, int out_size, void* d_ws, size_t ws_size,
                              hipStream_t stream) {
    const float* vel = (const float*)d_in[0];
    const float* Kv  = (const float*)d_in[1];
    const float* eps = (const float*)d_in[2];
    const float* Wc  = (const float*)d_in[3];
    const float* bc  = (const float*)d_in[4];
    const float* Wa  = (const float*)d_in[5];
    const float* ba  = (const float*)d_in[6];
    const float* Wm  = (const float*)d_in[7];
    const float* bm  = (const float*)d_in[8];
    float* out = (float*)d_out;

    char* ws = (char*)d_ws;
    float* amps   = (float*)(ws + 0);                  // 4 KB
    float* mean   = (float*)(ws + 4096);               // 4 KB
    float* pmax   = (float*)(ws + 8192);               // 4 KB
    float* costab = (float*)(ws + 12288);              // 16384 f = 64 KB
    float* Aimp   = (float*)(ws + 77824);              // 66*1024*4 = 270336
    short* imp_bf = (short*)(ws + 348160);             // 1024*1024*2 = 2 MiB
    short* revc   = (short*)(ws + 2445312);            // 8*9248*2 = 147968
    // total ws use: 2593280 bytes (~2.6 MB)

    k_head   <<<dim3(4),        dim3(256), 0, stream>>>(vel, Kv, Wa, ba, Wm, bm,
                                                        amps, mean, out + (size_t)NB * WIN);
    k_costab <<<dim3(328),      dim3(256), 0, stream>>>(costab, Aimp);
    k_maxpart<<<dim3(1024),     dim3(256), 0, stream>>>(eps, mean, pmax);
    k_nrev   <<<dim3(1),        dim3(256), 0, stream>>>(pmax, eps, mean, revc);
    k_apart  <<<dim3(4, 64),    dim3(256), 0, stream>>>(Wc, bc, costab, Aimp);
    k_hann   <<<dim3(264),      dim3(256), 0, stream>>>(Aimp);
    k_imp    <<<dim3(256),      dim3(256), 0, stream>>>(Aimp, vel, Kv, imp_bf);
    k_gemm   <<<dim3(64, 8),    dim3(256), 0, stream>>>(imp_bf, revc, amps, out);
}

// Round 3
// 264.830 us; speedup vs baseline: 1.8280x; 1.2653x over previous
//
#include <hip/hip_runtime.h>
#include <math.h>

// Problem constants
#define NB 1024        // batch
#define DF 64          // D_FEAT
#define WIN 8192       // WINDOW_SIZE
#define LIR 16382      // ir_len = 2*(WIN-1)
#define TBASE 7681     // t_j = TBASE + j
#define NJ 1024        // padded impulse length (real length 1023)
#define INV_MAXSTEPS (1.0f/2799.0f)
#define TWO_PI 6.28318530717958647692f

// rev-copy geometry: rev[x] = npad[9239-x]; revc[c][x] = rev[x+c], 8 copies, each padded to 9248 elems
#define REVLEN 9248
#define SREV 8212      // B[j][i] = rev[8212 - i + j]

using short8 = __attribute__((ext_vector_type(8))) short;
using f32x4  = __attribute__((ext_vector_type(4))) float;

static __device__ __forceinline__ short f2bf(float x) {
    unsigned u = __float_as_uint(x);
    unsigned r = (u + 0x7fffu + ((u >> 16) & 1u)) >> 16;   // RNE
    return (short)r;
}

// ---------------- K0: amps = sigmoid(x@Wa+ba), mean = tanh(x@Wm+bm) ----------------
__global__ void k_head(const float* __restrict__ vel, const float* __restrict__ Kv,
                       const float* __restrict__ Wa, const float* __restrict__ ba,
                       const float* __restrict__ Wm, const float* __restrict__ bm,
                       float* __restrict__ amps, float* __restrict__ mean,
                       float* __restrict__ out_mean) {
    int b = blockIdx.x * 256 + threadIdx.x;
    if (b >= NB) return;
    float sa = ba[0], sm = bm[0];
    #pragma unroll 8
    for (int d = 0; d < DF; ++d) {
        float v = vel[b * DF + d];
        sa = fmaf(v, Wa[d], sa);
        sm = fmaf(v, Wm[d], sm);
    }
    float xk = Kv[b] * INV_MAXSTEPS;
    sa = fmaf(xk, Wa[DF], sa);
    sm = fmaf(xk, Wm[DF], sm);
    amps[b] = 1.0f / (1.0f + expf(-sa));
    float m = tanhf(sm);
    mean[b] = m;
    out_mean[b] = m;
}

// ---------------- K0b: zero Aimp ----------------
__global__ void k_zero(float* __restrict__ Aimp) {
    int idx = blockIdx.x * 256 + threadIdx.x;
    if (idx < 66 * NJ) Aimp[idx] = 0.0f;
}

// ---------------- K1: per-block max of (mean[b] + eps[b,i]), float4 ----------------
__global__ void k_maxpart(const float* __restrict__ eps, const float* __restrict__ mean,
                          float* __restrict__ pmax) {
    __shared__ float red[256];
    int tid = threadIdx.x;
    float m = -INFINITY;
    const int total4 = NB * WIN / 4;
    const int stride = 1024 * 256;
    const float4* e4 = (const float4*)eps;
    for (int idx = blockIdx.x * 256 + tid; idx < total4; idx += stride) {
        int b = idx >> 11;                 // (idx*4)>>13
        float4 v = e4[idx];
        float mm = fmaxf(fmaxf(v.x, v.y), fmaxf(v.z, v.w));
        m = fmaxf(m, mean[b] + mm);
    }
    red[tid] = m;
    __syncthreads();
    for (int s = 128; s > 0; s >>= 1) {
        if (tid < s) red[tid] = fmaxf(red[tid], red[tid + s]);
        __syncthreads();
    }
    if (tid == 0) pmax[blockIdx.x] = red[0];
}

// ---------------- K1b: final max + write 8 shifted reversed bf16 noise copies ----------------
// npadval(q) = (q-517 in [0,8192)) ? (mean0+eps[q-517])/gmax : 0
// revc[c][x] = npadval(9239 - x - c), bf16
__global__ void k_nrev(const float* __restrict__ pmax, const float* __restrict__ eps,
                       const float* __restrict__ mean, short* __restrict__ revc) {
    __shared__ float red[256];
    int tid = threadIdx.x;
    float m = fmaxf(fmaxf(pmax[tid], pmax[tid + 256]),
                    fmaxf(pmax[tid + 512], pmax[tid + 768]));
    red[tid] = m;
    __syncthreads();
    for (int s = 128; s > 0; s >>= 1) {
        if (tid < s) red[tid] = fmaxf(red[tid], red[tid + s]);
        __syncthreads();
    }
    float inv = 1.0f / red[0];
    float m0 = mean[0];
    #pragma unroll
    for (int c = 0; c < 8; ++c) {
        for (int x = tid; x < REVLEN; x += 256) {
            int q = 9239 - x - c;
            int mm = q - 517;
            float v = ((unsigned)mm < (unsigned)WIN) ? (m0 + eps[mm]) * inv : 0.0f;
            revc[c * REVLEN + x] = f2bf(v);
        }
    }
}

// ---------------- K2: Aimp[d][j] += sum_{k in chunk} Waug[d][k] * c_k(t_j)  (atomic) ----------------
// c_k(t) = w_k/LIR * cos(2*pi*((k*t) mod LIR)/LIR) via v_cos_f32 (input in revolutions).
// d-split: 6 groups of 11 rows; grid (4 j-blocks, 6 d-groups, 32 k-chunks).
#define DSPLIT 6
#define DGROUP 11
#define KSPLIT 32
#define KCH (WIN / KSPLIT)     // 256
__global__ __launch_bounds__(256) void k_apart(const float* __restrict__ Wc,
                                               const float* __restrict__ bc,
                                               float* __restrict__ Aimp) {
    int tid = threadIdx.x;
    int j = blockIdx.x * 256 + tid;              // 0..1023
    int d0 = blockIdx.y * DGROUP;                // 0,11,...,55
    int k0 = blockIdx.z * KCH;
    int t = TBASE + j;
    int p = (k0 * t) % LIR;                      // k0*t <= 8192*8704 < 2^31

    const float* rows[DGROUP];
    #pragma unroll
    for (int dd = 0; dd < DGROUP; ++dd) {
        int d = d0 + dd;
        rows[dd] = (d < 65) ? (Wc + (size_t)d * WIN) : bc;
    }
    float acc[DGROUP];
    #pragma unroll
    for (int dd = 0; dd < DGROUP; ++dd) acc[dd] = 0.0f;

    #pragma unroll 4
    for (int kk = 0; kk < KCH; ++kk) {
        int k = k0 + kk;
        float cv = __builtin_amdgcn_cosf((float)p * (1.0f / (float)LIR));
        float w = (k == 0 || k == LIR / 2) ? (1.0f / (float)LIR) : (2.0f / (float)LIR);
        float c = cv * w;
        p += t; if (p >= LIR) p -= LIR;
        #pragma unroll
        for (int dd = 0; dd < DGROUP; ++dd)
            acc[dd] = fmaf(rows[dd][k], c, acc[dd]);
    }
    #pragma unroll
    for (int dd = 0; dd < DGROUP; ++dd)
        atomicAdd(Aimp + (d0 + dd) * NJ + j, acc[dd]);
}

// ---------------- K3: Aimp[d][j] *= hann(j+2); column 1023 zeroed (in place) ----------------
__global__ void k_hann(float* __restrict__ Aimp) {
    int idx = blockIdx.x * 256 + threadIdx.x;    // 0 .. 66*1024
    int j = idx & (NJ - 1);
    float w = 0.5f - 0.5f * cosf((float)(j + 2) * (TWO_PI / 1024.0f));
    if (j == NJ - 1) w = 0.0f;
    Aimp[idx] *= w;
}

// ---------------- K4: imp_bf[b][j] = bf16(xaug[b] . Aimp[:,j]) ----------------
__global__ void k_imp(const float* __restrict__ Aimp, const float* __restrict__ vel,
                      const float* __restrict__ Kv, short* __restrict__ imp_bf) {
    int tid = threadIdx.x;
    int b0 = blockIdx.x * 4;
    float acc[4][4];
    #pragma unroll
    for (int bb = 0; bb < 4; ++bb)
        #pragma unroll
        for (int q = 0; q < 4; ++q) acc[bb][q] = 0.0f;
    for (int d = 0; d < 65; ++d) {
        float xv[4];
        #pragma unroll
        for (int bb = 0; bb < 4; ++bb)
            xv[bb] = (d < DF) ? vel[(b0 + bb) * DF + d] : Kv[b0 + bb] * INV_MAXSTEPS;
        #pragma unroll
        for (int q = 0; q < 4; ++q) {
            float av = Aimp[d * NJ + q * 256 + tid];
            #pragma unroll
            for (int bb = 0; bb < 4; ++bb)
                acc[bb][q] = fmaf(xv[bb], av, acc[bb][q]);
        }
    }
    #pragma unroll
    for (int q = 0; q < 4; ++q) {
        float av = Aimp[65 * NJ + q * 256 + tid];
        #pragma unroll
        for (int bb = 0; bb < 4; ++bb)
            imp_bf[(size_t)(b0 + bb) * NJ + q * 256 + tid] = f2bf(acc[bb][q] + av);
    }
}

// ---------------- K5: MFMA GEMM  out[b][i] = amps[b] * sum_j imp[b][j]*rev[8212-i+j] ----------------
// Block = 256 thr = 4 waves (2x2), wave tile 64x64, block tile 128(M=b) x 128(N=i).
// A-frag: lane l holds imp[b0+mf*16+(l&15)][k0+8*(l>>4)+e], e=0..7 -> one 16B load.
// B-frag: lane l holds rev[8212-i+k], i = i0+nf*16+(l&15), k = k0+8*(l>>4)+e -> ascending
//         contiguous in rev; read copy c=(start&7) so the 8-run is 16B-aligned.
__global__ __launch_bounds__(256) void k_gemm(const short* __restrict__ imp_bf,
                                              const short* __restrict__ revc,
                                              const float* __restrict__ amps,
                                              float* __restrict__ out) {
    int tid = threadIdx.x;
    int l = tid & 63, w = tid >> 6;
    int wm = w >> 1, wn = w & 1;
    int lm = l & 15, lg = l >> 4;

    int brow0 = blockIdx.y * 128 + wm * 64;      // M base for this wave
    int icol0 = blockIdx.x * 128 + wn * 64;      // N base for this wave

    const short* pa[4];
    const short* pb[4];
    #pragma unroll
    for (int mf = 0; mf < 4; ++mf)
        pa[mf] = imp_bf + (size_t)(brow0 + mf * 16 + lm) * NJ + 8 * lg;
    #pragma unroll
    for (int nf = 0; nf < 4; ++nf) {
        int i = icol0 + nf * 16 + lm;
        int s0 = SREV - i + 8 * lg;              // at k0 = 0
        int c = s0 & 7;
        pb[nf] = revc + c * REVLEN + (s0 - c);
    }

    f32x4 acc[4][4];
    #pragma unroll
    for (int mf = 0; mf < 4; ++mf)
        #pragma unroll
        for (int nf = 0; nf < 4; ++nf)
            #pragma unroll
            for (int r = 0; r < 4; ++r) acc[mf][nf][r] = 0.0f;

    #pragma unroll 2
    for (int k0 = 0; k0 < NJ; k0 += 32) {
        short8 af[4], bfr[4];
        #pragma unroll
        for (int mf = 0; mf < 4; ++mf)
            af[mf] = *(const short8*)(pa[mf] + k0);
        #pragma unroll
        for (int nf = 0; nf < 4; ++nf)
            bfr[nf] = *(const short8*)(pb[nf] + k0);
        #pragma unroll
        for (int mf = 0; mf < 4; ++mf)
            #pragma unroll
            for (int nf = 0; nf < 4; ++nf)
                acc[mf][nf] = __builtin_amdgcn_mfma_f32_16x16x32_bf16(
                    af[mf], bfr[nf], acc[mf][nf], 0, 0, 0);
    }

    // D layout: col = lane&15, row = 4*(lane>>4) + r
    #pragma unroll
    for (int mf = 0; mf < 4; ++mf) {
        #pragma unroll
        for (int r = 0; r < 4; ++r) {
            int row = brow0 + mf * 16 + 4 * lg + r;
            float a = amps[row];
            #pragma unroll
            for (int nf = 0; nf < 4; ++nf)
                out[(size_t)row * WIN + icol0 + nf * 16 + lm] = a * acc[mf][nf][r];
        }
    }
}

// ---------------- launch ----------------
extern "C" void kernel_launch(void* const* d_in, const int* in_sizes, int n_in,
                              void* d_out, int out_size, void* d_ws, size_t ws_size,
                              hipStream_t stream) {
    const float* vel = (const float*)d_in[0];
    const float* Kv  = (const float*)d_in[1];
    const float* eps = (const float*)d_in[2];
    const float* Wc  = (const float*)d_in[3];
    const float* bc  = (const float*)d_in[4];
    const float* Wa  = (const float*)d_in[5];
    const float* ba  = (const float*)d_in[6];
    const float* Wm  = (const float*)d_in[7];
    const float* bm  = (const float*)d_in[8];
    float* out = (float*)d_out;

    char* ws = (char*)d_ws;
    float* amps   = (float*)(ws + 0);                  // 4 KB
    float* mean   = (float*)(ws + 4096);               // 4 KB
    float* pmax   = (float*)(ws + 8192);               // 4 KB
    float* Aimp   = (float*)(ws + 77824);              // 66*1024*4 = 270336
    short* imp_bf = (short*)(ws + 348160);             // 1024*1024*2 = 2 MiB
    short* revc   = (short*)(ws + 2445312);            // 8*9248*2 = 147968
    // total ws use: ~2.6 MB

    k_head   <<<dim3(4),          dim3(256), 0, stream>>>(vel, Kv, Wa, ba, Wm, bm,
                                                          amps, mean, out + (size_t)NB * WIN);
    k_zero   <<<dim3(264),        dim3(256), 0, stream>>>(Aimp);
    k_maxpart<<<dim3(1024),       dim3(256), 0, stream>>>(eps, mean, pmax);
    k_nrev   <<<dim3(1),          dim3(256), 0, stream>>>(pmax, eps, mean, revc);
    k_apart  <<<dim3(4, 6, KSPLIT), dim3(256), 0, stream>>>(Wc, bc, Aimp);
    k_hann   <<<dim3(264),        dim3(256), 0, stream>>>(Aimp);
    k_imp    <<<dim3(256),        dim3(256), 0, stream>>>(Aimp, vel, Kv, imp_bf);
    k_gemm   <<<dim3(64, 8),      dim3(256), 0, stream>>>(imp_bf, revc, amps, out);
}

// Round 4
// 210.353 us; speedup vs baseline: 2.3014x; 1.2590x over previous
//
#include <hip/hip_runtime.h>
#include <math.h>

// Problem constants
#define NB 1024        // batch
#define DF 64          // D_FEAT
#define WIN 8192       // WINDOW_SIZE
#define LIR 16382      // ir_len = 2*(WIN-1)
#define TBASE 7681     // t_j = TBASE + j
#define NJ 1024        // padded impulse length (real length 1023)
#define INV_MAXSTEPS (1.0f/2799.0f)
#define TWO_PI 6.28318530717958647692f

// rev-copy geometry: rev[x] = npad[9239-x]; revc[c][x] = rev[x+c], 8 copies, padded to 9248
#define REVLEN 9248
#define SREV 8212      // B[j][i] = rev[8212 - i + j]

using short8 = __attribute__((ext_vector_type(8))) short;
using f32x4  = __attribute__((ext_vector_type(4))) float;

static __device__ __forceinline__ short f2bf(float x) {
    unsigned u = __float_as_uint(x);
    unsigned r = (u + 0x7fffu + ((u >> 16) & 1u)) >> 16;   // RNE
    return (short)r;
}

// ---------------- K0: amps = sigmoid(x@Wa+ba), mean = tanh(x@Wm+bm) ----------------
__global__ void k_head(const float* __restrict__ vel, const float* __restrict__ Kv,
                       const float* __restrict__ Wa, const float* __restrict__ ba,
                       const float* __restrict__ Wm, const float* __restrict__ bm,
                       float* __restrict__ amps, float* __restrict__ mean,
                       float* __restrict__ out_mean) {
    int b = blockIdx.x * 256 + threadIdx.x;
    if (b >= NB) return;
    float sa = ba[0], sm = bm[0];
    #pragma unroll 8
    for (int d = 0; d < DF; ++d) {
        float v = vel[b * DF + d];
        sa = fmaf(v, Wa[d], sa);
        sm = fmaf(v, Wm[d], sm);
    }
    float xk = Kv[b] * INV_MAXSTEPS;
    sa = fmaf(xk, Wa[DF], sa);
    sm = fmaf(xk, Wm[DF], sm);
    amps[b] = 1.0f / (1.0f + expf(-sa));
    float m = tanhf(sm);
    mean[b] = m;
    out_mean[b] = m;
}

// ---------------- K_prep: Ct gen (into d_out scratch) + Waug bf16 + Aimp zero ----------------
// Ct[j][k] = hann(j+2) * w_k * cos(2*pi*((k*t_j) mod LIR)/LIR), bf16, row j=1023 zero.
// Waug[d][k]: d<65 -> Wc row d; d==65 -> bc; 66..79 -> 0.  Aimp[80*1024] = 0.
#define PREP_CT_BLK 4096
#define PREP_W_BLK  320
#define PREP_Z_BLK  80
__global__ __launch_bounds__(256) void k_prep(const float* __restrict__ Wc,
                                              const float* __restrict__ bc,
                                              short* __restrict__ Ct,
                                              short* __restrict__ Waug,
                                              float* __restrict__ Aimp) {
    int bx = blockIdx.x, tid = threadIdx.x;
    if (bx < PREP_CT_BLK) {
        int flat = bx * 2048 + tid * 8;
        int j = flat >> 13, k0 = flat & 8191;
        int t = TBASE + j;
        int p = (k0 * t) % LIR;                      // exact, k0*t < 2^31
        float hw = 0.5f - 0.5f * __builtin_amdgcn_cosf((float)(j + 2) * (1.0f / 1024.0f));
        if (j == NJ - 1) hw = 0.0f;
        short8 v;
        #pragma unroll
        for (int e = 0; e < 8; ++e) {
            int k = k0 + e;
            float w = (k == 0 || k == LIR / 2) ? (1.0f / (float)LIR) : (2.0f / (float)LIR);
            float c = __builtin_amdgcn_cosf((float)p * (1.0f / (float)LIR)) * w * hw;
            v[e] = f2bf(c);
            p += t; if (p >= LIR) p -= LIR;
        }
        *(short8*)(Ct + flat) = v;
    } else if (bx < PREP_CT_BLK + PREP_W_BLK) {
        int flat = (bx - PREP_CT_BLK) * 2048 + tid * 8;
        int d = flat >> 13, k0 = flat & 8191;
        short8 v;
        #pragma unroll
        for (int e = 0; e < 8; ++e) {
            float x = 0.0f;
            if (d < 65)       x = Wc[(size_t)d * WIN + k0 + e];
            else if (d == 65) x = bc[k0 + e];
            v[e] = f2bf(x);
        }
        *(short8*)(Waug + flat) = v;
    } else {
        int idx = ((bx - PREP_CT_BLK - PREP_W_BLK) * 256 + tid) * 4;
        float4 z = {0.0f, 0.0f, 0.0f, 0.0f};
        *(float4*)(Aimp + idx) = z;
    }
}

// ---------------- K1: per-block max of (mean[b] + eps[b,i]), float4 ----------------
__global__ void k_maxpart(const float* __restrict__ eps, const float* __restrict__ mean,
                          float* __restrict__ pmax) {
    __shared__ float red[256];
    int tid = threadIdx.x;
    float m = -INFINITY;
    const int total4 = NB * WIN / 4;
    const int stride = 1024 * 256;
    const float4* e4 = (const float4*)eps;
    for (int idx = blockIdx.x * 256 + tid; idx < total4; idx += stride) {
        int b = idx >> 11;
        float4 v = e4[idx];
        float mm = fmaxf(fmaxf(v.x, v.y), fmaxf(v.z, v.w));
        m = fmaxf(m, mean[b] + mm);
    }
    red[tid] = m;
    __syncthreads();
    for (int s = 128; s > 0; s >>= 1) {
        if (tid < s) red[tid] = fmaxf(red[tid], red[tid + s]);
        __syncthreads();
    }
    if (tid == 0) pmax[blockIdx.x] = red[0];
}

// ---------------- K_gmax: reduce 1024 pmax -> gmb = {1/gmax, mean[0]} ----------------
__global__ void k_gmax(const float* __restrict__ pmax, const float* __restrict__ mean,
                       float* __restrict__ gmb) {
    __shared__ float red[256];
    int tid = threadIdx.x;
    float m = fmaxf(fmaxf(pmax[tid], pmax[tid + 256]),
                    fmaxf(pmax[tid + 512], pmax[tid + 768]));
    red[tid] = m;
    __syncthreads();
    for (int s = 128; s > 0; s >>= 1) {
        if (tid < s) red[tid] = fmaxf(red[tid], red[tid + s]);
        __syncthreads();
    }
    if (tid == 0) { gmb[0] = 1.0f / red[0]; gmb[1] = mean[0]; }
}

// ---------------- K_nrevm: revc[c][x] = bf16(npadval(9239-x-c)), multi-block ----------------
__global__ void k_nrevm(const float* __restrict__ gmb, const float* __restrict__ eps,
                        short* __restrict__ revc) {
    int c = blockIdx.y;
    int x = blockIdx.x * 256 + threadIdx.x;
    if (x >= REVLEN) return;
    float inv = gmb[0], m0 = gmb[1];
    int q = 9239 - x - c;
    int mm = q - 517;
    float v = ((unsigned)mm < (unsigned)WIN) ? (m0 + eps[mm]) * inv : 0.0f;
    revc[c * REVLEN + x] = f2bf(v);
}

// ---------------- K_gemmA: Aimp[d][j] += sum_k Ct[j][k]*Waug[d][k]  (MFMA, atomic) ----------------
// M=j (1024), N=d (80), K=8192. Wave: 2 m-frags x 5 n-frags. Grid (8 m-blocks, 32 k-chunks).
#define GA_KCH 256
__global__ __launch_bounds__(256) void k_gemmA(const short* __restrict__ Ct,
                                               const short* __restrict__ Waug,
                                               float* __restrict__ Aimp) {
    int tid = threadIdx.x;
    int l = tid & 63, w = tid >> 6;
    int lm = l & 15, lg = l >> 4;
    int m0 = blockIdx.x * 128 + w * 32;          // j base for this wave
    int k0 = blockIdx.y * GA_KCH;

    const short* pa[2];
    #pragma unroll
    for (int mf = 0; mf < 2; ++mf)
        pa[mf] = Ct + (size_t)(m0 + mf * 16 + lm) * WIN + k0 + 8 * lg;
    const short* pb[5];
    #pragma unroll
    for (int nf = 0; nf < 5; ++nf)
        pb[nf] = Waug + (size_t)(nf * 16 + lm) * WIN + k0 + 8 * lg;

    f32x4 acc[2][5];
    #pragma unroll
    for (int mf = 0; mf < 2; ++mf)
        #pragma unroll
        for (int nf = 0; nf < 5; ++nf)
            #pragma unroll
            for (int r = 0; r < 4; ++r) acc[mf][nf][r] = 0.0f;

    #pragma unroll 2
    for (int kk = 0; kk < GA_KCH; kk += 32) {
        short8 a0 = *(const short8*)(pa[0] + kk);
        short8 a1 = *(const short8*)(pa[1] + kk);
        short8 bb[5];
        #pragma unroll
        for (int nf = 0; nf < 5; ++nf) bb[nf] = *(const short8*)(pb[nf] + kk);
        #pragma unroll
        for (int nf = 0; nf < 5; ++nf) {
            acc[0][nf] = __builtin_amdgcn_mfma_f32_16x16x32_bf16(a0, bb[nf], acc[0][nf], 0, 0, 0);
            acc[1][nf] = __builtin_amdgcn_mfma_f32_16x16x32_bf16(a1, bb[nf], acc[1][nf], 0, 0, 0);
        }
    }
    // D: row(j) = m0 + mf*16 + 4*lg + r, col(d) = nf*16 + lm
    #pragma unroll
    for (int mf = 0; mf < 2; ++mf)
        #pragma unroll
        for (int nf = 0; nf < 5; ++nf)
            #pragma unroll
            for (int r = 0; r < 4; ++r)
                atomicAdd(Aimp + (nf * 16 + lm) * NJ + (m0 + mf * 16 + 4 * lg + r),
                          acc[mf][nf][r]);
}

// ---------------- K4: imp_bf[b][j] = bf16(xaug[b] . Aimp[:,j]) ----------------
__global__ void k_imp(const float* __restrict__ Aimp, const float* __restrict__ vel,
                      const float* __restrict__ Kv, short* __restrict__ imp_bf) {
    int tid = threadIdx.x;
    int b0 = blockIdx.x * 4;
    float acc[4][4];
    #pragma unroll
    for (int bb = 0; bb < 4; ++bb)
        #pragma unroll
        for (int q = 0; q < 4; ++q) acc[bb][q] = 0.0f;
    for (int d = 0; d < 65; ++d) {
        float xv[4];
        #pragma unroll
        for (int bb = 0; bb < 4; ++bb)
            xv[bb] = (d < DF) ? vel[(b0 + bb) * DF + d] : Kv[b0 + bb] * INV_MAXSTEPS;
        #pragma unroll
        for (int q = 0; q < 4; ++q) {
            float av = Aimp[d * NJ + q * 256 + tid];
            #pragma unroll
            for (int bb = 0; bb < 4; ++bb)
                acc[bb][q] = fmaf(xv[bb], av, acc[bb][q]);
        }
    }
    #pragma unroll
    for (int q = 0; q < 4; ++q) {
        float av = Aimp[65 * NJ + q * 256 + tid];
        #pragma unroll
        for (int bb = 0; bb < 4; ++bb)
            imp_bf[(size_t)(b0 + bb) * NJ + q * 256 + tid] = f2bf(acc[bb][q] + av);
    }
}

// ---------------- K5: MFMA GEMM  out[b][i] = amps[b] * sum_j imp[b][j]*rev[8212-i+j] ----------------
__global__ __launch_bounds__(256) void k_gemm(const short* __restrict__ imp_bf,
                                              const short* __restrict__ revc,
                                              const float* __restrict__ amps,
                                              float* __restrict__ out) {
    int tid = threadIdx.x;
    int l = tid & 63, w = tid >> 6;
    int wm = w >> 1, wn = w & 1;
    int lm = l & 15, lg = l >> 4;

    int brow0 = blockIdx.y * 128 + wm * 64;
    int icol0 = blockIdx.x * 128 + wn * 64;

    const short* pa[4];
    const short* pb[4];
    #pragma unroll
    for (int mf = 0; mf < 4; ++mf)
        pa[mf] = imp_bf + (size_t)(brow0 + mf * 16 + lm) * NJ + 8 * lg;
    #pragma unroll
    for (int nf = 0; nf < 4; ++nf) {
        int i = icol0 + nf * 16 + lm;
        int s0 = SREV - i + 8 * lg;
        int c = s0 & 7;
        pb[nf] = revc + c * REVLEN + (s0 - c);
    }

    f32x4 acc[4][4];
    #pragma unroll
    for (int mf = 0; mf < 4; ++mf)
        #pragma unroll
        for (int nf = 0; nf < 4; ++nf)
            #pragma unroll
            for (int r = 0; r < 4; ++r) acc[mf][nf][r] = 0.0f;

    #pragma unroll 2
    for (int k0 = 0; k0 < NJ; k0 += 32) {
        short8 af[4], bfr[4];
        #pragma unroll
        for (int mf = 0; mf < 4; ++mf)
            af[mf] = *(const short8*)(pa[mf] + k0);
        #pragma unroll
        for (int nf = 0; nf < 4; ++nf)
            bfr[nf] = *(const short8*)(pb[nf] + k0);
        #pragma unroll
        for (int mf = 0; mf < 4; ++mf)
            #pragma unroll
            for (int nf = 0; nf < 4; ++nf)
                acc[mf][nf] = __builtin_amdgcn_mfma_f32_16x16x32_bf16(
                    af[mf], bfr[nf], acc[mf][nf], 0, 0, 0);
    }

    #pragma unroll
    for (int mf = 0; mf < 4; ++mf) {
        #pragma unroll
        for (int r = 0; r < 4; ++r) {
            int row = brow0 + mf * 16 + 4 * lg + r;
            float a = amps[row];
            #pragma unroll
            for (int nf = 0; nf < 4; ++nf)
                out[(size_t)row * WIN + icol0 + nf * 16 + lm] = a * acc[mf][nf][r];
        }
    }
}

// ---------------- launch ----------------
extern "C" void kernel_launch(void* const* d_in, const int* in_sizes, int n_in,
                              void* d_out, int out_size, void* d_ws, size_t ws_size,
                              hipStream_t stream) {
    const float* vel = (const float*)d_in[0];
    const float* Kv  = (const float*)d_in[1];
    const float* eps = (const float*)d_in[2];
    const float* Wc  = (const float*)d_in[3];
    const float* bc  = (const float*)d_in[4];
    const float* Wa  = (const float*)d_in[5];
    const float* ba  = (const float*)d_in[6];
    const float* Wm  = (const float*)d_in[7];
    const float* bm  = (const float*)d_in[8];
    float* out = (float*)d_out;

    char* ws = (char*)d_ws;
    float* amps   = (float*)(ws + 0);                  // 4 KB
    float* mean   = (float*)(ws + 4096);               // 4 KB
    float* pmax   = (float*)(ws + 8192);               // 4 KB
    float* gmb    = (float*)(ws + 12288);              // 16 B
    float* Aimp   = (float*)(ws + 16384);              // 80*1024*4 = 327680
    short* imp_bf = (short*)(ws + 344064);             // 1024*1024*2 = 2 MiB
    short* Waug   = (short*)(ws + 2441216);            // 80*8192*2 = 1310720
    short* revc   = (short*)(ws + 3751936);            // 8*9248*2 = 147968 -> ends 3899904
    short* Ct     = (short*)d_out;                     // 16.8 MB scratch inside out (33.5 MB),
                                                       // fully overwritten by k_gemm afterwards

    k_head   <<<dim3(4),                      dim3(256), 0, stream>>>(vel, Kv, Wa, ba, Wm, bm,
                                                                      amps, mean, out + (size_t)NB * WIN);
    k_prep   <<<dim3(PREP_CT_BLK + PREP_W_BLK + PREP_Z_BLK), dim3(256), 0, stream>>>(Wc, bc, Ct, Waug, Aimp);
    k_maxpart<<<dim3(1024),                   dim3(256), 0, stream>>>(eps, mean, pmax);
    k_gmax   <<<dim3(1),                      dim3(256), 0, stream>>>(pmax, mean, gmb);
    k_nrevm  <<<dim3(37, 8),                  dim3(256), 0, stream>>>(gmb, eps, revc);
    k_gemmA  <<<dim3(8, 32),                  dim3(256), 0, stream>>>(Ct, Waug, Aimp);
    k_imp    <<<dim3(256),                    dim3(256), 0, stream>>>(Aimp, vel, Kv, imp_bf);
    k_gemm   <<<dim3(64, 8),                  dim3(256), 0, stream>>>(imp_bf, revc, amps, out);
}

// Round 5
// 165.137 us; speedup vs baseline: 2.9316x; 1.2738x over previous
//
#include <hip/hip_runtime.h>
#include <math.h>

// Problem constants
#define NB 1024        // batch
#define DF 64          // D_FEAT
#define WIN 8192       // WINDOW_SIZE
#define LIR 16382      // ir_len = 2*(WIN-1)
#define TBASE 7681     // t_j = TBASE + j
#define NJ 1024        // padded impulse length (real length 1023)
#define INV_MAXSTEPS (1.0f/2799.0f)
#define TWO_PI 6.28318530717958647692f

// rev-copy geometry: rev[x] = npad[9239-x]; revc[c][x] = rev[x+c], 8 copies, padded to 9248
#define REVLEN 9248
#define SREV 8212      // B[j][i] = rev[8212 - i + j]

// LDS B-window: per block, window of rev covering i in [icol0,icol0+128), k in [0,1024)
#define BW_ELEMS 1160          // per-copy elements (145 x 8)
#define BW_CHUNKS 145

using short8 = __attribute__((ext_vector_type(8))) short;
using f32x4  = __attribute__((ext_vector_type(4))) float;

static __device__ __forceinline__ short f2bf(float x) {
    unsigned u = __float_as_uint(x);
    unsigned r = (u + 0x7fffu + ((u >> 16) & 1u)) >> 16;   // RNE
    return (short)r;
}

// ---------------- K0: amps = sigmoid(x@Wa+ba), mean = tanh(x@Wm+bm) ----------------
__global__ void k_head(const float* __restrict__ vel, const float* __restrict__ Kv,
                       const float* __restrict__ Wa, const float* __restrict__ ba,
                       const float* __restrict__ Wm, const float* __restrict__ bm,
                       float* __restrict__ amps, float* __restrict__ mean,
                       float* __restrict__ out_mean) {
    int b = blockIdx.x * 256 + threadIdx.x;
    if (b >= NB) return;
    float sa = ba[0], sm = bm[0];
    #pragma unroll 8
    for (int d = 0; d < DF; ++d) {
        float v = vel[b * DF + d];
        sa = fmaf(v, Wa[d], sa);
        sm = fmaf(v, Wm[d], sm);
    }
    float xk = Kv[b] * INV_MAXSTEPS;
    sa = fmaf(xk, Wa[DF], sa);
    sm = fmaf(xk, Wm[DF], sm);
    amps[b] = 1.0f / (1.0f + expf(-sa));
    float m = tanhf(sm);
    mean[b] = m;
    out_mean[b] = m;
}

// ---------------- K_prep: Ct gen (into d_out scratch) + Waug bf16 ----------------
// Ct[j][k] = hann(j+2) * w_k * cos(2*pi*((k*t_j) mod LIR)/LIR), bf16, row j=1023 zero.
// Waug[d][k]: d<65 -> Wc row d; d==65 -> bc; 66..79 -> 0.
#define PREP_CT_BLK 4096
#define PREP_W_BLK  320
__global__ __launch_bounds__(256) void k_prep(const float* __restrict__ Wc,
                                              const float* __restrict__ bc,
                                              short* __restrict__ Ct,
                                              short* __restrict__ Waug) {
    int bx = blockIdx.x, tid = threadIdx.x;
    if (bx < PREP_CT_BLK) {
        int flat = bx * 2048 + tid * 8;
        int j = flat >> 13, k0 = flat & 8191;
        int t = TBASE + j;
        int p = (k0 * t) % LIR;                      // exact, k0*t < 2^31
        float hw = 0.5f - 0.5f * __builtin_amdgcn_cosf((float)(j + 2) * (1.0f / 1024.0f));
        if (j == NJ - 1) hw = 0.0f;
        short8 v;
        #pragma unroll
        for (int e = 0; e < 8; ++e) {
            int k = k0 + e;
            float w = (k == 0 || k == LIR / 2) ? (1.0f / (float)LIR) : (2.0f / (float)LIR);
            float c = __builtin_amdgcn_cosf((float)p * (1.0f / (float)LIR)) * w * hw;
            v[e] = f2bf(c);
            p += t; if (p >= LIR) p -= LIR;
        }
        *(short8*)(Ct + flat) = v;
    } else {
        int flat = (bx - PREP_CT_BLK) * 2048 + tid * 8;
        int d = flat >> 13, k0 = flat & 8191;
        short8 v;
        #pragma unroll
        for (int e = 0; e < 8; ++e) {
            float x = 0.0f;
            if (d < 65)       x = Wc[(size_t)d * WIN + k0 + e];
            else if (d == 65) x = bc[k0 + e];
            v[e] = f2bf(x);
        }
        *(short8*)(Waug + flat) = v;
    }
}

// ---------------- K1: per-block max of (mean[b] + eps[b,i]), float4 ----------------
__global__ void k_maxpart(const float* __restrict__ eps, const float* __restrict__ mean,
                          float* __restrict__ pmax) {
    __shared__ float red[256];
    int tid = threadIdx.x;
    float m = -INFINITY;
    const int total4 = NB * WIN / 4;
    const int stride = 1024 * 256;
    const float4* e4 = (const float4*)eps;
    for (int idx = blockIdx.x * 256 + tid; idx < total4; idx += stride) {
        int b = idx >> 11;
        float4 v = e4[idx];
        float mm = fmaxf(fmaxf(v.x, v.y), fmaxf(v.z, v.w));
        m = fmaxf(m, mean[b] + mm);
    }
    red[tid] = m;
    __syncthreads();
    for (int s = 128; s > 0; s >>= 1) {
        if (tid < s) red[tid] = fmaxf(red[tid], red[tid + s]);
        __syncthreads();
    }
    if (tid == 0) pmax[blockIdx.x] = red[0];
}

// ---------------- K_gmax: reduce 1024 pmax -> gmb = {1/gmax, mean[0]} ----------------
__global__ void k_gmax(const float* __restrict__ pmax, const float* __restrict__ mean,
                       float* __restrict__ gmb) {
    __shared__ float red[256];
    int tid = threadIdx.x;
    float m = fmaxf(fmaxf(pmax[tid], pmax[tid + 256]),
                    fmaxf(pmax[tid + 512], pmax[tid + 768]));
    red[tid] = m;
    __syncthreads();
    for (int s = 128; s > 0; s >>= 1) {
        if (tid < s) red[tid] = fmaxf(red[tid], red[tid + s]);
        __syncthreads();
    }
    if (tid == 0) { gmb[0] = 1.0f / red[0]; gmb[1] = mean[0]; }
}

// ---------------- K_nrevm: revc[c][x] = bf16(npadval(9239-x-c)), multi-block ----------------
__global__ void k_nrevm(const float* __restrict__ gmb, const float* __restrict__ eps,
                        short* __restrict__ revc) {
    int c = blockIdx.y;
    int x = blockIdx.x * 256 + threadIdx.x;
    if (x >= REVLEN) return;
    float inv = gmb[0], m0 = gmb[1];
    int q = 9239 - x - c;
    int mm = q - 517;
    float v = ((unsigned)mm < (unsigned)WIN) ? (m0 + eps[mm]) * inv : 0.0f;
    revc[c * REVLEN + x] = f2bf(v);
}

// ---------------- K_gemmA: Apart[ky][j][d] = sum_{k chunk ky} Ct[j][k]*Waug[d][k] ----------------
// M=j (1024), N=d (80), K=8192. Wave: 2 m-frags x 5 n-frags. Grid (8 m-blocks, 32 k-chunks).
#define GA_KCH 256
__global__ __launch_bounds__(256) void k_gemmA(const short* __restrict__ Ct,
                                               const short* __restrict__ Waug,
                                               float* __restrict__ Apart) {
    int tid = threadIdx.x;
    int l = tid & 63, w = tid >> 6;
    int lm = l & 15, lg = l >> 4;
    int m0 = blockIdx.x * 128 + w * 32;          // j base for this wave
    int ky = blockIdx.y;
    int k0 = ky * GA_KCH;

    const short* pa[2];
    #pragma unroll
    for (int mf = 0; mf < 2; ++mf)
        pa[mf] = Ct + (size_t)(m0 + mf * 16 + lm) * WIN + k0 + 8 * lg;
    const short* pb[5];
    #pragma unroll
    for (int nf = 0; nf < 5; ++nf)
        pb[nf] = Waug + (size_t)(nf * 16 + lm) * WIN + k0 + 8 * lg;

    f32x4 acc[2][5];
    #pragma unroll
    for (int mf = 0; mf < 2; ++mf)
        #pragma unroll
        for (int nf = 0; nf < 5; ++nf)
            #pragma unroll
            for (int r = 0; r < 4; ++r) acc[mf][nf][r] = 0.0f;

    #pragma unroll 2
    for (int kk = 0; kk < GA_KCH; kk += 32) {
        short8 a0 = *(const short8*)(pa[0] + kk);
        short8 a1 = *(const short8*)(pa[1] + kk);
        short8 bb[5];
        #pragma unroll
        for (int nf = 0; nf < 5; ++nf) bb[nf] = *(const short8*)(pb[nf] + kk);
        #pragma unroll
        for (int nf = 0; nf < 5; ++nf) {
            acc[0][nf] = __builtin_amdgcn_mfma_f32_16x16x32_bf16(a0, bb[nf], acc[0][nf], 0, 0, 0);
            acc[1][nf] = __builtin_amdgcn_mfma_f32_16x16x32_bf16(a1, bb[nf], acc[1][nf], 0, 0, 0);
        }
    }
    // D: row(j) = m0 + mf*16 + 4*lg + r, col(d) = nf*16 + lm
    float* base = Apart + (size_t)ky * (NJ * 80);
    #pragma unroll
    for (int mf = 0; mf < 2; ++mf)
        #pragma unroll
        for (int r = 0; r < 4; ++r) {
            int j = m0 + mf * 16 + 4 * lg + r;
            #pragma unroll
            for (int nf = 0; nf < 5; ++nf)
                base[(size_t)j * 80 + nf * 16 + lm] = acc[mf][nf][r];
        }
}

// ---------------- K_red: Aimp[d][j] = sum_ky Apart[ky][j][d] ----------------
__global__ __launch_bounds__(256) void k_red(const float* __restrict__ Apart,
                                             float* __restrict__ Aimp) {
    int flat = blockIdx.x * 256 + threadIdx.x;   // 0 .. 81920
    float s = 0.0f;
    #pragma unroll 8
    for (int ky = 0; ky < 32; ++ky)
        s += Apart[(size_t)ky * (NJ * 80) + flat];
    int j = flat / 80, d = flat - j * 80;
    Aimp[d * NJ + j] = s;
}

// ---------------- K4: imp_bf[b][j] = bf16(xaug[b] . Aimp[:,j]) ----------------
__global__ void k_imp(const float* __restrict__ Aimp, const float* __restrict__ vel,
                      const float* __restrict__ Kv, short* __restrict__ imp_bf) {
    int tid = threadIdx.x;
    int b0 = blockIdx.x * 4;
    float acc[4][4];
    #pragma unroll
    for (int bb = 0; bb < 4; ++bb)
        #pragma unroll
        for (int q = 0; q < 4; ++q) acc[bb][q] = 0.0f;
    for (int d = 0; d < 65; ++d) {
        float xv[4];
        #pragma unroll
        for (int bb = 0; bb < 4; ++bb)
            xv[bb] = (d < DF) ? vel[(b0 + bb) * DF + d] : Kv[b0 + bb] * INV_MAXSTEPS;
        #pragma unroll
        for (int q = 0; q < 4; ++q) {
            float av = Aimp[d * NJ + q * 256 + tid];
            #pragma unroll
            for (int bb = 0; bb < 4; ++bb)
                acc[bb][q] = fmaf(xv[bb], av, acc[bb][q]);
        }
    }
    #pragma unroll
    for (int q = 0; q < 4; ++q) {
        float av = Aimp[65 * NJ + q * 256 + tid];
        #pragma unroll
        for (int bb = 0; bb < 4; ++bb)
            imp_bf[(size_t)(b0 + bb) * NJ + q * 256 + tid] = f2bf(acc[bb][q] + av);
    }
}

// ---------------- K5: LDS-tiled MFMA GEMM ----------------
// out[b][i] = amps[b] * sum_j imp[b][j]*rev[SREV-i+j]
// Block tile 128(M=b) x 128(N=i), BK=64, 4 waves (2x2), wave tile 64x64.
// sA: double-buffered [128][64] bf16 with XOR swizzle byte^((row&7)<<4) (write+read).
// sB: full Toeplitz window, 8 shift-copies x 1160 bf16, staged once.
__global__ __launch_bounds__(256) void k_gemm(const short* __restrict__ imp_bf,
                                              const short* __restrict__ revc,
                                              const float* __restrict__ amps,
                                              float* __restrict__ out) {
    __shared__ short sA[2][128 * 64];
    __shared__ short sB[8 * BW_ELEMS];
    int tid = threadIdx.x;
    int bid = blockIdx.x;
    int m_idx = bid & 7;                 // XCD-affine: same m-slab stays on one XCD
    int n_idx = bid >> 3;
    int brow0 = m_idx * 128;
    int icol0 = n_idx * 128;
    int wbase = 8080 - icol0;            // (SREV - icol0 - 127) rounded down to mult of 8

    // ---- stage sB (once): copy c holds rev[wbase + u + c] = revc[c][wbase + u] ----
    for (int q = tid; q < 8 * BW_CHUNKS; q += 256) {
        int c = q / BW_CHUNKS;
        int u8 = (q - c * BW_CHUNKS) * 8;
        *(float4*)(sB + q * 8) = *(const float4*)(revc + c * REVLEN + wbase + u8);
    }

    // ---- stage A chunk 0 ----
    float4 st[4];
    #pragma unroll
    for (int it = 0; it < 4; ++it) {
        int q = it * 256 + tid;
        int row = q >> 3, c16 = q & 7;
        st[it] = *(const float4*)(imp_bf + (size_t)(brow0 + row) * NJ + c16 * 8);
    }
    #pragma unroll
    for (int it = 0; it < 4; ++it) {
        int q = it * 256 + tid;
        int row = q >> 3, c16 = q & 7;
        int db = row * 128 + ((c16 * 16) ^ ((row & 7) << 4));
        *(float4*)((char*)sA[0] + db) = st[it];
    }

    // ---- wave/lane geometry ----
    int l = tid & 63, w = tid >> 6;
    int wm = w >> 1, wn = w & 1;
    int lm = l & 15, lg = l >> 4;

    // A-frag LDS offsets (shorts), swizzled
    int aoff[4][2];
    #pragma unroll
    for (int mf = 0; mf < 4; ++mf)
        #pragma unroll
        for (int kki = 0; kki < 2; ++kki) {
            int row = wm * 64 + mf * 16 + lm;
            int kb = (kki * 32 + 8 * lg) * 2;
            aoff[mf][kki] = row * 64 + ((kb ^ ((row & 7) << 4)) >> 1);
        }
    // B-frag LDS offsets (shorts): copy index is k-invariant
    int boff[4];
    #pragma unroll
    for (int nf = 0; nf < 4; ++nf) {
        int i = icol0 + wn * 64 + nf * 16 + lm;
        int snf = SREV - i;
        int c = snf & 7;
        boff[nf] = c * BW_ELEMS + (snf - c - wbase) + 8 * lg;
    }

    f32x4 acc[4][4];
    #pragma unroll
    for (int mf = 0; mf < 4; ++mf)
        #pragma unroll
        for (int nf = 0; nf < 4; ++nf)
            #pragma unroll
            for (int r = 0; r < 4; ++r) acc[mf][nf][r] = 0.0f;

    int p = 0;
    for (int ch = 0; ch < 16; ++ch) {
        __syncthreads();
        // prefetch next A chunk into regs (lands under this chunk's MFMAs)
        if (ch < 15) {
            int k0n = (ch + 1) * 64;
            #pragma unroll
            for (int it = 0; it < 4; ++it) {
                int q = it * 256 + tid;
                int row = q >> 3, c16 = q & 7;
                st[it] = *(const float4*)(imp_bf + (size_t)(brow0 + row) * NJ + k0n + c16 * 8);
            }
        }
        int k0 = ch * 64;
        #pragma unroll
        for (int kki = 0; kki < 2; ++kki) {
            short8 af[4], bfr[4];
            #pragma unroll
            for (int mf = 0; mf < 4; ++mf)
                af[mf] = *(const short8*)(sA[p] + aoff[mf][kki]);
            #pragma unroll
            for (int nf = 0; nf < 4; ++nf)
                bfr[nf] = *(const short8*)(sB + boff[nf] + k0 + kki * 32);
            #pragma unroll
            for (int mf = 0; mf < 4; ++mf)
                #pragma unroll
                for (int nf = 0; nf < 4; ++nf)
                    acc[mf][nf] = __builtin_amdgcn_mfma_f32_16x16x32_bf16(
                        af[mf], bfr[nf], acc[mf][nf], 0, 0, 0);
        }
        // write prefetched chunk into the other buffer
        if (ch < 15) {
            #pragma unroll
            for (int it = 0; it < 4; ++it) {
                int q = it * 256 + tid;
                int row = q >> 3, c16 = q & 7;
                int db = row * 128 + ((c16 * 16) ^ ((row & 7) << 4));
                *(float4*)((char*)sA[p ^ 1] + db) = st[it];
            }
        }
        p ^= 1;
    }

    // D: row = 4*lg + r (+frag base), col = lm (+frag base)
    #pragma unroll
    for (int mf = 0; mf < 4; ++mf) {
        #pragma unroll
        for (int r = 0; r < 4; ++r) {
            int row = brow0 + wm * 64 + mf * 16 + 4 * lg + r;
            float a = amps[row];
            #pragma unroll
            for (int nf = 0; nf < 4; ++nf)
                out[(size_t)row * WIN + icol0 + wn * 64 + nf * 16 + lm] = a * acc[mf][nf][r];
        }
    }
}

// ---------------- launch ----------------
extern "C" void kernel_launch(void* const* d_in, const int* in_sizes, int n_in,
                              void* d_out, int out_size, void* d_ws, size_t ws_size,
                              hipStream_t stream) {
    const float* vel = (const float*)d_in[0];
    const float* Kv  = (const float*)d_in[1];
    const float* eps = (const float*)d_in[2];
    const float* Wc  = (const float*)d_in[3];
    const float* bc  = (const float*)d_in[4];
    const float* Wa  = (const float*)d_in[5];
    const float* ba  = (const float*)d_in[6];
    const float* Wm  = (const float*)d_in[7];
    const float* bm  = (const float*)d_in[8];
    float* out = (float*)d_out;

    char* ws = (char*)d_ws;
    float* amps   = (float*)(ws + 0);                  // 4 KB
    float* mean   = (float*)(ws + 4096);               // 4 KB
    float* pmax   = (float*)(ws + 8192);               // 4 KB
    float* gmb    = (float*)(ws + 12288);              // 16 B
    float* Aimp   = (float*)(ws + 16384);              // 80*1024*4 = 327680
    short* imp_bf = (short*)(ws + 344064);             // 1024*1024*2 = 2 MiB
    short* Waug   = (short*)(ws + 2441216);            // 80*8192*2 = 1310720
    short* revc   = (short*)(ws + 3751936);            // 8*9248*2 = 147968 -> ends 3899904

    // d_out scratch regions (fully overwritten by k_gemm / final outputs at the end):
    short* Ct    = (short*)d_out;                      // 16.8 MB
    float* Apart = (float*)((char*)d_out + 16777216);  // 32*1024*80*4 = 10.5 MB (ends 27.3 MB)

    k_head   <<<dim3(4),                      dim3(256), 0, stream>>>(vel, Kv, Wa, ba, Wm, bm,
                                                                      amps, mean, out + (size_t)NB * WIN);
    k_prep   <<<dim3(PREP_CT_BLK + PREP_W_BLK), dim3(256), 0, stream>>>(Wc, bc, Ct, Waug);
    k_maxpart<<<dim3(1024),                   dim3(256), 0, stream>>>(eps, mean, pmax);
    k_gmax   <<<dim3(1),                      dim3(256), 0, stream>>>(pmax, mean, gmb);
    k_nrevm  <<<dim3(37, 8),                  dim3(256), 0, stream>>>(gmb, eps, revc);
    k_gemmA  <<<dim3(8, 32),                  dim3(256), 0, stream>>>(Ct, Waug, Apart);
    k_red    <<<dim3(320),                    dim3(256), 0, stream>>>(Apart, Aimp);
    k_imp    <<<dim3(256),                    dim3(256), 0, stream>>>(Aimp, vel, Kv, imp_bf);
    k_gemm   <<<dim3(512),                    dim3(256), 0, stream>>>(imp_bf, revc, amps, out);
}